// Round 2
// baseline (185.078 us; speedup 1.0000x reference)
//
#include <hip/hip_runtime.h>
#include <hip/hip_bf16.h>
#include <math.h>

#define Bn 8
#define Cn 1152
#define Nn 1024  // H*W

typedef short short8 __attribute__((ext_vector_type(8)));
typedef float f32x4 __attribute__((ext_vector_type(4)));

// Intermediates. Fully overwritten every call (poison-safe).
__device__ float g_csum_part[Bn * 32 * Nn];  // per-(b, seg) partial column sums
__device__ float g_icsum[Bn * Nn];           // 1/colsum
__device__ unsigned short g_A[(size_t)Bn * Nn * Nn];  // E[b][i][j] = exp(w) (unnormalized)

__device__ inline unsigned short f2bf(float x) {
    __hip_bfloat16 h = __float2bfloat16(x);
    unsigned short u;
    __builtin_memcpy(&u, &h, 2);
    return u;
}

__device__ inline void inv3(const float* M, float* o) {
    float a = M[0], b = M[1], c = M[2];
    float d = M[3], e = M[4], f = M[5];
    float g = M[6], h = M[7], i = M[8];
    float A0 = (e * i - f * h);
    float A1 = -(d * i - f * g);
    float A2 = (d * h - e * g);
    float det = a * A0 + b * A1 + c * A2;
    float inv = 1.0f / det;
    o[0] = A0 * inv;
    o[1] = -(b * i - c * h) * inv;
    o[2] = (b * f - c * e) * inv;
    o[3] = A1 * inv;
    o[4] = (a * i - c * g) * inv;
    o[5] = -(a * f - c * d) * inv;
    o[6] = A2 * inv;
    o[7] = -(a * h - b * g) * inv;
    o[8] = (a * e - b * d) * inv;
}

__device__ inline void mm3(const float* X, const float* Y, float* Z) {
    for (int r = 0; r < 3; r++)
        for (int c = 0; c < 3; c++)
            Z[r * 3 + c] = X[r * 3 + 0] * Y[0 * 3 + c] + X[r * 3 + 1] * Y[1 * 3 + c] +
                           X[r * 3 + 2] * Y[2 * 3 + c];
}

// F = inv(K2^T) skew(t) R inv(K1). SVD in the reference is a rank-2 no-op
// (skew(t)@R already has singular values (|t|,|t|,0)). Thread 0 per block.
__device__ inline void computeF(const float* K1, const float* K2, const float* R,
                                const float* t, int b, float* F) {
    float t0 = t[b * 3 + 0], t1 = t[b * 3 + 1], t2 = t[b * 3 + 2];
    float S[9] = {0.0f, -t2, t1, t2, 0.0f, -t0, -t1, t0, 0.0f};
    float E[9];
    mm3(S, &R[b * 9], E);
    float iK1[9], iK2[9];
    inv3(&K1[b * 9], iK1);
    inv3(&K2[b * 9], iK2);
    float iK2T[9] = {iK2[0], iK2[3], iK2[6], iK2[1], iK2[4], iK2[7], iK2[2], iK2[5], iK2[8]};
    float T[9];
    mm3(iK2T, E, T);
    mm3(T, iK1, F);
}

// Per-j coefficients: z_ij = |ix*P + iy*Q - R| - 0.5  (== 5*(d_epi - 0.1))
__device__ inline float4 zcoef(const float* F, int j) {
    float jx = (float)(j >> 5);
    float jy = (float)(j & 31);
    float l0 = F[0] * jx + F[1] * jy + F[2];
    float l1 = F[3] * jx + F[4] * jy + F[5];
    float l2 = F[6] * jx + F[7] * jy + F[8];
    l0 = l0 / l2;
    l1 = l1 / l2;
    float y0 = -1.0f / l1;
    float y1 = -(1.0f + l0 * 32.0f) / l1;
    float dy = y0 - y1;
    float invn = 1.0f / sqrtf(1024.0f + dy * dy);
    return make_float4(5.0f * dy * invn, 160.0f * invn, 160.0f * y0 * invn, 0.0f);
}

// Fused prep: per (b, seg) block of 32 rows, compute z once per (i,j), do the
// row softmax in-wave (full row per wave, lane owns j = lane+64k), emit
// E = exp(1 - rowsoftmax) as bf16 + per-(b,seg) partial column sums.
// Grid 256: lin&7 = b = XCD.
__launch_bounds__(256) __global__ void fusedE_kernel(const float* __restrict__ K1,
                                                     const float* __restrict__ K2,
                                                     const float* __restrict__ R,
                                                     const float* __restrict__ t) {
    __shared__ float Fs[9];
    __shared__ float4 prm[Nn];        // 16 KB
    __shared__ float red[4][16][64];  // 16 KB, per-wave csum partials
    int lin = blockIdx.x;
    int b = lin & 7;
    int seg = lin >> 3;  // 0..31
    if (threadIdx.x == 0) computeF(K1, K2, R, t, b, Fs);
    __syncthreads();
#pragma unroll
    for (int u = 0; u < 4; u++) {
        int j = threadIdx.x * 4 + u;
        prm[j] = zcoef(Fs, j);
    }
    __syncthreads();
    int wv = threadIdx.x >> 6;
    int lane = threadIdx.x & 63;
    float px[16], py[16], pz[16];
#pragma unroll
    for (int k = 0; k < 16; k++) {
        float4 p = prm[lane + k * 64];
        px[k] = p.x;
        py[k] = p.y;
        pz[k] = p.z;
    }
    float csum[16];
#pragma unroll
    for (int k = 0; k < 16; k++) csum[k] = 0.0f;
#pragma unroll
    for (int rr = 0; rr < 8; rr++) {
        int i = seg * 32 + wv * 8 + rr;
        float ix = (float)(i >> 5), iy = (float)(i & 31);
        float e[16], m = -INFINITY;
#pragma unroll
        for (int k = 0; k < 16; k++) {
            e[k] = fabsf(fmaf(ix, px[k], fmaf(iy, py[k], -pz[k]))) - 0.5f;
            m = fmaxf(m, e[k]);
        }
#pragma unroll
        for (int o = 32; o > 0; o >>= 1) m = fmaxf(m, __shfl_xor(m, o, 64));
        float s = 0.0f;
#pragma unroll
        for (int k = 0; k < 16; k++) {
            e[k] = __expf(e[k] - m);  // reused below
            s += e[k];
        }
#pragma unroll
        for (int o = 32; o > 0; o >>= 1) s += __shfl_xor(s, o, 64);
        float rsi = 1.0f / s;
        unsigned short* arow = g_A + (size_t)(b * Nn + i) * Nn;
#pragma unroll
        for (int k = 0; k < 16; k++) {
            float E = __expf(1.0f - e[k] * rsi);
            csum[k] += E;
            arow[lane + k * 64] = f2bf(E);
        }
    }
#pragma unroll
    for (int k = 0; k < 16; k++) red[wv][k][lane] = csum[k];
    __syncthreads();
    int l2 = threadIdx.x & 63;
    int k0 = (threadIdx.x >> 6) * 4;
#pragma unroll
    for (int q = 0; q < 4; q++) {
        int k = k0 + q;
        float ssum = red[0][k][l2] + red[1][k][l2] + red[2][k][l2] + red[3][k][l2];
        g_csum_part[(b * 32 + seg) * Nn + k * 64 + l2] = ssum;
    }
}

// Finalize 1/colsum. Grid 8 (one per batch). Same accumulation order as the
// old convert kernel (it = 0..31 float4 adds) -> bit-identical results.
__global__ void icsum_kernel() {
    int b = blockIdx.x;
    int j0 = threadIdx.x * 4;
    float4 cs = *(const float4*)&g_csum_part[(b * 32 + 0) * Nn + j0];
#pragma unroll
    for (int it = 1; it < 32; it++) {
        float4 p = *(const float4*)&g_csum_part[(b * 32 + it) * Nn + j0];
        cs.x += p.x; cs.y += p.y; cs.z += p.z; cs.w += p.w;
    }
    float4 inv = make_float4(1.0f / cs.x, 1.0f / cs.y, 1.0f / cs.z, 1.0f / cs.w);
    *(float4*)&g_icsum[b * Nn + j0] = inv;
}

// out[b,i,c] = sum_j E[b,i,j] * (f_src[b,c,j]/csum[b,j]).
// The 1/csum scale + f32->bf16 convert is folded into B-staging (no g_fb pass).
// 128(i) x 64(c) tile, 256 threads = 4 waves, each wave 64x32 (4x2 mfma tiles).
// Grid 1152 = 4.5 blocks/CU x 4 waves = 18 waves/CU (2x round-1's 9: the
// vmcnt(0)-drain barrier is covered by other resident blocks' MFMA).
// lin&7 = b = XCD; consecutive s share the f_src c-panel for L2 reuse.
#define BM 128
#define BNc 64
#define BK 32

__launch_bounds__(256, 4) __global__ void gemm_kernel(const float* __restrict__ fsrc,
                                                      float* __restrict__ out) {
    __shared__ unsigned short As[2][BM * BK];   // 8 KB each
    __shared__ unsigned short Bs[2][BNc * BK];  // 4 KB each
    __shared__ float ics[Nn];                   // 4 KB
    int lin = blockIdx.x;
    int b = lin & 7;
    int s = lin >> 3;  // 0..143
    int it = s & 7;
    int ct = s >> 3;   // 0..17
    int i0 = it * BM;
    int c0 = ct * BNc;
    int t = threadIdx.x;
    int w = t >> 6, L = t & 63;
    int wr = w >> 1, wc = w & 1;  // wave -> 64x32 sub-tile
    const unsigned short* Ab = g_A + (size_t)b * Nn * Nn + (size_t)i0 * Nn;
    const float* Fb = fsrc + ((size_t)b * Cn + c0) * Nn;

#pragma unroll
    for (int u = 0; u < 4; u++) {
        int j = t + u * 256;
        ics[j] = g_icsum[b * Nn + j];
    }

    auto stage = [&](int p, int kt) {
        // A: 512 x 16B chunks, 2/thread, async direct-to-LDS
#pragma unroll
        for (int h = 0; h < 2; h++) {
            int chunk = h * 256 + t;                 // 0..511
            int rr = chunk >> 2;                     // row 0..127
            int gq = (chunk & 3) ^ ((rr >> 1) & 3);  // swizzled global k-quad
            const unsigned short* ga = Ab + (size_t)rr * Nn + kt + gq * 8;
            __builtin_amdgcn_global_load_lds(
                (const __attribute__((address_space(1))) unsigned int*)ga,
                (__attribute__((address_space(3))) unsigned int*)(As[p] + chunk * 8), 16, 0, 0);
        }
        // B: 256 x 16B chunks, 1/thread: f32 load, scale by 1/csum, cvt bf16
        {
            int chunk = t;                           // 0..255
            int rr = chunk >> 2;                     // row (c) 0..63
            int gq = (chunk & 3) ^ ((rr >> 1) & 3);
            const float* gb = Fb + (size_t)rr * Nn + kt + gq * 8;
            float4 v0 = *(const float4*)gb;
            float4 v1 = *(const float4*)(gb + 4);
            const float* icp = &ics[kt + gq * 8];
            ushort4 u0, u1;
            u0.x = f2bf(v0.x * icp[0]);
            u0.y = f2bf(v0.y * icp[1]);
            u0.z = f2bf(v0.z * icp[2]);
            u0.w = f2bf(v0.w * icp[3]);
            u1.x = f2bf(v1.x * icp[4]);
            u1.y = f2bf(v1.y * icp[5]);
            u1.z = f2bf(v1.z * icp[6]);
            u1.w = f2bf(v1.w * icp[7]);
            *(ushort4*)(Bs[p] + chunk * 8) = u0;
            *(ushort4*)(Bs[p] + chunk * 8 + 4) = u1;
        }
    };

    f32x4 acc[4][2] = {};
    int lrow = L & 15, quad = L >> 4;
    __syncthreads();  // ics visible before first B staging
    stage(0, 0);
    for (int kt = 0; kt < Nn; kt += BK) {
        int p = (kt >> 5) & 1;
        __syncthreads();  // buffer p staged (vmcnt+lgkm); prev compute retired
        if (kt + BK < Nn) stage(1 - p, kt + BK);  // in flight during compute below
        short8 af[4], bf[2];
#pragma unroll
        for (int mt = 0; mt < 4; mt++) {
            int rr = wr * 64 + mt * 16 + lrow;
            int q = quad ^ ((rr >> 1) & 3);
            af[mt] = *(const short8*)(As[p] + rr * BK + q * 8);
        }
#pragma unroll
        for (int nt = 0; nt < 2; nt++) {
            int cc = wc * 32 + nt * 16 + lrow;
            int q = quad ^ ((cc >> 1) & 3);
            bf[nt] = *(const short8*)(Bs[p] + cc * BK + q * 8);
        }
#pragma unroll
        for (int mt = 0; mt < 4; mt++)
#pragma unroll
            for (int nt = 0; nt < 2; nt++)
                acc[mt][nt] =
                    __builtin_amdgcn_mfma_f32_16x16x32_bf16(af[mt], bf[nt], acc[mt][nt], 0, 0, 0);
    }
    // Epilogue: D col=lane&15, row=(lane>>4)*4+reg  [m89-verified]
    int col = L & 15;
#pragma unroll
    for (int mt = 0; mt < 4; mt++)
#pragma unroll
        for (int rg = 0; rg < 4; rg++) {
            int i = i0 + wr * 64 + mt * 16 + quad * 4 + rg;
            float* orow = out + ((size_t)b * Nn + i) * Cn + c0 + wc * 32;
#pragma unroll
            for (int nt = 0; nt < 2; nt++) orow[nt * 16 + col] = acc[mt][nt][rg];
        }
}

extern "C" void kernel_launch(void* const* d_in, const int* in_sizes, int n_in,
                              void* d_out, int out_size, void* d_ws, size_t ws_size,
                              hipStream_t stream) {
    (void)in_sizes; (void)n_in; (void)d_ws; (void)ws_size; (void)out_size;
    const float* f_src = (const float*)d_in[1];  // d_in[0] = f_tar unused by reference
    const float* K1 = (const float*)d_in[2];
    const float* K2 = (const float*)d_in[3];
    const float* R = (const float*)d_in[4];
    const float* t = (const float*)d_in[5];
    float* out = (float*)d_out;

    fusedE_kernel<<<dim3(256), dim3(256), 0, stream>>>(K1, K2, R, t);
    icsum_kernel<<<dim3(8), dim3(256), 0, stream>>>();
    gemm_kernel<<<dim3(Bn * (Nn / BM) * (Cn / BNc)), dim3(256), 0, stream>>>(f_src, out);
}